// Round 1
// baseline (4095.439 us; speedup 1.0000x reference)
//
#include <hip/hip_runtime.h>

// DefSeq: def-sequence LSTM + GRU-gated RNN + vocab projection, MI355X gfx950.
// Strategy R1: recurrence via bf16-MFMA with hi/lo split (3-term, ~fp32 accurate);
// final [1024x1024]@[1024x32000]^T projection via plain bf16 MFMA 128x128 tiles.

typedef __bf16 bf16;
typedef __bf16 bf16x8 __attribute__((ext_vector_type(8)));
typedef __bf16 bf16x4v __attribute__((ext_vector_type(4)));
typedef float f32x4 __attribute__((ext_vector_type(4)));

#define Vv 32000
#define Ee 512
#define Hh 1024
#define Ss 32
#define Bb 32
#define KC 1536  // E + H

static __device__ __forceinline__ float sigf(float x) { return 1.0f / (1.0f + __expf(-x)); }

// ---------------- weight conversion: fp32 -> bf16 hi/lo pairs ----------------

// Wg[j][0:512] = Wih[j], Wg[j][512:1536] = Whh[j]   (j in [0,4096))
__global__ void k_conv_cat_cols(const float* __restrict__ A, const float* __restrict__ Bm,
                                bf16* __restrict__ hi, bf16* __restrict__ lo) {
  int j = blockIdx.y;
  int k = blockIdx.x * 256 + threadIdx.x;
  float v = (k < Ee) ? A[(size_t)j * Ee + k] : Bm[(size_t)j * Hh + (k - Ee)];
  bf16 h = (bf16)v;
  hi[(size_t)j * KC + k] = h;
  lo[(size_t)j * KC + k] = (bf16)(v - (float)h);
}

// Wzr rows [0,1024) = Wz, rows [1024,1536) = Wr  (K = 1536 both)
__global__ void k_conv_cat_rows(const float* __restrict__ A, const float* __restrict__ Bm,
                                bf16* __restrict__ hi, bf16* __restrict__ lo) {
  int j = blockIdx.y;
  int k = blockIdx.x * 256 + threadIdx.x;
  float v = (j < Hh) ? A[(size_t)j * KC + k] : Bm[(size_t)(j - Hh) * KC + k];
  bf16 h = (bf16)v;
  hi[(size_t)j * KC + k] = h;
  lo[(size_t)j * KC + k] = (bf16)(v - (float)h);
}

__global__ void k_conv_plain(const float* __restrict__ A, bf16* __restrict__ hi,
                             bf16* __restrict__ lo) {
  int j = blockIdx.y;
  int k = blockIdx.x * 256 + threadIdx.x;
  float v = A[(size_t)j * KC + k];
  bf16 h = (bf16)v;
  hi[(size_t)j * KC + k] = h;
  lo[(size_t)j * KC + k] = (bf16)(v - (float)h);
}

// ---------------- gathers ----------------

__global__ void k_gather_we(const int* __restrict__ word, const float* __restrict__ emb,
                            float* __restrict__ we, bf16* __restrict__ x2h, bf16* __restrict__ x2l) {
  int b = blockIdx.y;
  int e = blockIdx.x * 256 + threadIdx.x;
  float v = emb[(size_t)word[b] * Ee + e];
  we[b * Ee + e] = v;
  bf16 h = (bf16)v;
  x2h[(size_t)b * KC + e] = h;
  x2l[(size_t)b * KC + e] = (bf16)(v - (float)h);
}

__global__ void k_gather_se(const int* __restrict__ seq, const float* __restrict__ emb,
                            bf16* __restrict__ se_h, bf16* __restrict__ se_l) {
  int tb = blockIdx.y;  // t*32 + b
  int e = blockIdx.x * 256 + threadIdx.x;
  float v = emb[(size_t)seq[tb] * Ee + e];
  bf16 h = (bf16)v;
  se_h[(size_t)tb * Ee + e] = h;
  se_l[(size_t)tb * Ee + e] = (bf16)(v - (float)h);
}

// h0 = we @ Wl.T + bl ; c = h0 ; hp = bf16split(h0).  fp32, wave-per-output.
__global__ void k_init_h0(const float* __restrict__ we, const float* __restrict__ Wl,
                          const float* __restrict__ bl, float* __restrict__ c,
                          bf16* __restrict__ hp_h, bf16* __restrict__ hp_l) {
  int o = blockIdx.x * 4 + (threadIdx.x >> 6);  // 0..32767
  int lane = threadIdx.x & 63;
  int b = o >> 10, n = o & 1023;
  const float* wr = we + b * Ee;
  const float* wl = Wl + (size_t)n * Ee;
  int e0 = lane * 8;
  float4 a0 = *(const float4*)(wr + e0);
  float4 a1 = *(const float4*)(wr + e0 + 4);
  float4 b0 = *(const float4*)(wl + e0);
  float4 b1 = *(const float4*)(wl + e0 + 4);
  float s = a0.x * b0.x + a0.y * b0.y + a0.z * b0.z + a0.w * b0.w +
            a1.x * b1.x + a1.y * b1.y + a1.z * b1.z + a1.w * b1.w;
  for (int off = 32; off; off >>= 1) s += __shfl_down(s, off);
  if (lane == 0) {
    s += bl[n];
    c[o] = s;
    bf16 h = (bf16)s;
    hp_h[o] = h;
    hp_l[o] = (bf16)(s - (float)h);
  }
}

// ---------------- recurrent step kernels (M=32, K=1536, bf16 hi/lo 3-term MFMA) -------

// GEMM1: gates = [x_t | h_prev] @ [Wih|Whh].T ; LSTM pointwise -> c, h_lstm
// grid 64 blocks: block owns 16 k-columns across all 4 gate slabs; wave w = slab w.
__global__ __launch_bounds__(256) void k_step_gates(
    const bf16* __restrict__ se_h, const bf16* __restrict__ se_l, int t,
    const bf16* __restrict__ hp_h, const bf16* __restrict__ hp_l,
    const bf16* __restrict__ Wg_h, const bf16* __restrict__ Wg_l,
    const float* __restrict__ bih, const float* __restrict__ bhh,
    float* __restrict__ c, float* __restrict__ hl_f32,
    bf16* __restrict__ x2h, bf16* __restrict__ x2l,
    bf16* __restrict__ x3h, bf16* __restrict__ x3l) {
  int tid = threadIdx.x;
  int w = tid >> 6, lane = tid & 63;
  int l16 = lane & 15, quad = lane >> 4;
  int k0 = blockIdx.x * 16;
  int j0 = w * Hh + k0;
  const bf16* se_th = se_h + (size_t)t * Bb * Ee;
  const bf16* se_tl = se_l + (size_t)t * Bb * Ee;

  f32x4 acc[2][3];
#pragma unroll
  for (int mt = 0; mt < 2; ++mt)
#pragma unroll
    for (int q = 0; q < 3; ++q) acc[mt][q] = (f32x4){0.f, 0.f, 0.f, 0.f};

  for (int kk = 0; kk < KC; kk += 32) {
    bf16x8 bh_ = *(const bf16x8*)(Wg_h + (size_t)(j0 + l16) * KC + kk + quad * 8);
    bf16x8 bl_ = *(const bf16x8*)(Wg_l + (size_t)(j0 + l16) * KC + kk + quad * 8);
#pragma unroll
    for (int mt = 0; mt < 2; ++mt) {
      int b = mt * 16 + l16;
      const bf16 *pah, *pal;
      if (kk < Ee) {
        pah = se_th + (size_t)b * Ee + kk;
        pal = se_tl + (size_t)b * Ee + kk;
      } else {
        pah = hp_h + (size_t)b * Hh + (kk - Ee);
        pal = hp_l + (size_t)b * Hh + (kk - Ee);
      }
      bf16x8 ah = *(const bf16x8*)(pah + quad * 8);
      bf16x8 al = *(const bf16x8*)(pal + quad * 8);
      acc[mt][0] = __builtin_amdgcn_mfma_f32_16x16x32_bf16(ah, bh_, acc[mt][0], 0, 0, 0);
      acc[mt][1] = __builtin_amdgcn_mfma_f32_16x16x32_bf16(al, bh_, acc[mt][1], 0, 0, 0);
      acc[mt][2] = __builtin_amdgcn_mfma_f32_16x16x32_bf16(ah, bl_, acc[mt][2], 0, 0, 0);
    }
  }

  __shared__ float g_lds[4][Bb][16];
#pragma unroll
  for (int mt = 0; mt < 2; ++mt)
#pragma unroll
    for (int r = 0; r < 4; ++r) {
      int b = mt * 16 + quad * 4 + r;
      int j = j0 + l16;
      g_lds[w][b][l16] = acc[mt][0][r] + acc[mt][1][r] + acc[mt][2][r] + bih[j] + bhh[j];
    }
  __syncthreads();
#pragma unroll
  for (int i = 0; i < 2; ++i) {
    int idx = tid + i * 256;  // 0..511 = 32b x 16k
    int b = idx >> 4, kk = idx & 15;
    int kg = k0 + kk;
    float gi = g_lds[0][b][kk], gf = g_lds[1][b][kk];
    float gg = g_lds[2][b][kk], go = g_lds[3][b][kk];
    float co = c[b * Hh + kg];
    float cn = sigf(gf) * co + sigf(gi) * tanhf(gg);
    float hl = sigf(go) * tanhf(cn);
    c[b * Hh + kg] = cn;
    hl_f32[b * Hh + kg] = hl;
    bf16 hb = (bf16)hl;
    bf16 lb = (bf16)(hl - (float)hb);
    x2h[(size_t)b * KC + Ee + kg] = hb;
    x2l[(size_t)b * KC + Ee + kg] = lb;
    x3h[(size_t)b * KC + Ee + kg] = hb;
    x3l[(size_t)b * KC + Ee + kg] = lb;
  }
}

// shared 3-term accumulate core for zr / hh (A rows stride KC)
static __device__ __forceinline__ void mma3(const bf16* __restrict__ Ah, const bf16* __restrict__ Al,
                                            const bf16* __restrict__ Bh, const bf16* __restrict__ Bl,
                                            int rowB, int l16, int quad, f32x4 acc[2][3]) {
  for (int kk = 0; kk < KC; kk += 32) {
    bf16x8 bh_ = *(const bf16x8*)(Bh + (size_t)rowB * KC + kk + quad * 8);
    bf16x8 bl_ = *(const bf16x8*)(Bl + (size_t)rowB * KC + kk + quad * 8);
#pragma unroll
    for (int mt = 0; mt < 2; ++mt) {
      int b = mt * 16 + l16;
      bf16x8 ah = *(const bf16x8*)(Ah + (size_t)b * KC + kk + quad * 8);
      bf16x8 al = *(const bf16x8*)(Al + (size_t)b * KC + kk + quad * 8);
      acc[mt][0] = __builtin_amdgcn_mfma_f32_16x16x32_bf16(ah, bh_, acc[mt][0], 0, 0, 0);
      acc[mt][1] = __builtin_amdgcn_mfma_f32_16x16x32_bf16(al, bh_, acc[mt][1], 0, 0, 0);
      acc[mt][2] = __builtin_amdgcn_mfma_f32_16x16x32_bf16(ah, bl_, acc[mt][2], 0, 0, 0);
    }
  }
}

// GEMM2: [z; r] = sigmoid([we|h_lstm] @ [Wz;Wr].T + [bz;br]) ; x3 left = r*we
// grid 24 blocks x 4 waves x 16 rows.
__global__ __launch_bounds__(256) void k_step_zr(
    const bf16* __restrict__ x2h, const bf16* __restrict__ x2l,
    const bf16* __restrict__ Wzr_h, const bf16* __restrict__ Wzr_l,
    const float* __restrict__ bz, const float* __restrict__ br, const float* __restrict__ we,
    float* __restrict__ z_f32, bf16* __restrict__ x3h, bf16* __restrict__ x3l) {
  int tid = threadIdx.x;
  int w = tid >> 6, lane = tid & 63;
  int l16 = lane & 15, quad = lane >> 4;
  int j0 = blockIdx.x * 64 + w * 16;

  f32x4 acc[2][3];
#pragma unroll
  for (int mt = 0; mt < 2; ++mt)
#pragma unroll
    for (int q = 0; q < 3; ++q) acc[mt][q] = (f32x4){0.f, 0.f, 0.f, 0.f};
  mma3(x2h, x2l, Wzr_h, Wzr_l, j0 + l16, l16, quad, acc);

  int j = j0 + l16;
#pragma unroll
  for (int mt = 0; mt < 2; ++mt)
#pragma unroll
    for (int r = 0; r < 4; ++r) {
      int b = mt * 16 + quad * 4 + r;
      float val = acc[mt][0][r] + acc[mt][1][r] + acc[mt][2][r];
      if (j < Hh) {
        z_f32[b * Hh + j] = sigf(val + bz[j]);
      } else {
        int e = j - Hh;
        float rv = sigf(val + br[e]) * we[b * Ee + e];
        bf16 hb = (bf16)rv;
        x3h[(size_t)b * KC + e] = hb;
        x3l[(size_t)b * KC + e] = (bf16)(rv - (float)hb);
      }
    }
}

// GEMM3: hh = tanh([r*we|h_lstm] @ Wh.T + bh); h = (1-z)h_lstm + z*hh
// grid 16 blocks.
__global__ __launch_bounds__(256) void k_step_hh(
    const bf16* __restrict__ x3h, const bf16* __restrict__ x3l,
    const bf16* __restrict__ Wh_h, const bf16* __restrict__ Wh_l, const float* __restrict__ bh,
    const float* __restrict__ hl_f32, const float* __restrict__ z_f32, float* __restrict__ h_f32,
    bf16* __restrict__ hp_h, bf16* __restrict__ hp_l, bf16* __restrict__ hs_b, int t) {
  int tid = threadIdx.x;
  int w = tid >> 6, lane = tid & 63;
  int l16 = lane & 15, quad = lane >> 4;
  int j0 = blockIdx.x * 64 + w * 16;

  f32x4 acc[2][3];
#pragma unroll
  for (int mt = 0; mt < 2; ++mt)
#pragma unroll
    for (int q = 0; q < 3; ++q) acc[mt][q] = (f32x4){0.f, 0.f, 0.f, 0.f};
  mma3(x3h, x3l, Wh_h, Wh_l, j0 + l16, l16, quad, acc);

  int j = j0 + l16;
#pragma unroll
  for (int mt = 0; mt < 2; ++mt)
#pragma unroll
    for (int r = 0; r < 4; ++r) {
      int b = mt * 16 + quad * 4 + r;
      float hhv = tanhf(acc[mt][0][r] + acc[mt][1][r] + acc[mt][2][r] + bh[j]);
      float hl = hl_f32[b * Hh + j];
      float zz = z_f32[b * Hh + j];
      float hn = (1.f - zz) * hl + zz * hhv;
      h_f32[b * Hh + j] = hn;
      bf16 hb = (bf16)hn;
      hp_h[b * Hh + j] = hb;
      hp_l[b * Hh + j] = (bf16)(hn - (float)hb);
      hs_b[((size_t)t * Bb + b) * Hh + j] = hb;
    }
}

// ---------------- final projection: out = hs @ Wo.T + bo  (bf16 MFMA, 128x128 tiles) ----

__global__ __launch_bounds__(256) void k_gemm_out(const bf16* __restrict__ hs,
                                                  const float* __restrict__ Wo,
                                                  const float* __restrict__ bo,
                                                  float* __restrict__ out) {
  // swizzle so all 8 mi-blocks of one ni land on the same XCD (id % 8 heuristic)
  int id = blockIdx.x;
  int r_ = id & 7, s_ = id >> 3;
  int mi = s_ & 7;
  int ni = (s_ >> 3) * 8 + r_;
  if (ni >= Vv / 128) return;
  int m0 = mi * 128, n0 = ni * 128;

  int tid = threadIdx.x;
  int w = tid >> 6, lane = tid & 63;
  int l16 = lane & 15, quad = lane >> 4;
  int wm = w & 1, wn = w >> 1;

  __shared__ bf16 A_lds[128 * 32];
  __shared__ bf16 B_lds[128 * 32];

  f32x4 acc[4][4];
#pragma unroll
  for (int i = 0; i < 4; ++i)
#pragma unroll
    for (int j = 0; j < 4; ++j) acc[i][j] = (f32x4){0.f, 0.f, 0.f, 0.f};

  for (int kt = 0; kt < 32; ++kt) {
    int k0 = kt * 32;
    // stage A (bf16, 8KB): 2 x 16B per thread
#pragma unroll
    for (int i = 0; i < 2; ++i) {
      int cid = tid + i * 256;
      int row = cid >> 2, ch = cid & 3;
      *(int4*)&A_lds[row * 32 + ch * 8] =
          *(const int4*)&hs[(size_t)(m0 + row) * Hh + k0 + ch * 8];
    }
    // stage B (fp32 -> bf16, 16KB read): 4 x 16B per thread
#pragma unroll
    for (int i = 0; i < 4; ++i) {
      int cid = tid + i * 256;
      int row = cid >> 3, ch = cid & 7;
      float4 v = *(const float4*)&Wo[(size_t)(n0 + row) * Hh + k0 + ch * 4];
      bf16x4v bv = {(bf16)v.x, (bf16)v.y, (bf16)v.z, (bf16)v.w};
      *(bf16x4v*)&B_lds[row * 32 + ch * 4] = bv;
    }
    __syncthreads();

    const bf16* Ab = &A_lds[(wm * 64 + l16) * 32 + quad * 8];
    const bf16* Bx = &B_lds[(wn * 64 + l16) * 32 + quad * 8];
    bf16x8 af[4], bfr[4];
#pragma unroll
    for (int i = 0; i < 4; ++i) af[i] = *(const bf16x8*)(Ab + i * 16 * 32);
#pragma unroll
    for (int j = 0; j < 4; ++j) bfr[j] = *(const bf16x8*)(Bx + j * 16 * 32);
#pragma unroll
    for (int i = 0; i < 4; ++i)
#pragma unroll
      for (int j = 0; j < 4; ++j)
        acc[i][j] = __builtin_amdgcn_mfma_f32_16x16x32_bf16(af[i], bfr[j], acc[i][j], 0, 0, 0);
    __syncthreads();
  }

#pragma unroll
  for (int i = 0; i < 4; ++i)
#pragma unroll
    for (int j = 0; j < 4; ++j)
#pragma unroll
      for (int r = 0; r < 4; ++r) {
        int m = m0 + wm * 64 + i * 16 + quad * 4 + r;
        int n = n0 + wn * 64 + j * 16 + l16;
        out[(size_t)m * Vv + n] = acc[i][j][r] + bo[n];
      }
}

__global__ void k_copy_hc(const float* __restrict__ h_f32, const float* __restrict__ c_f32,
                          float* __restrict__ out) {
  int i = blockIdx.x * 256 + threadIdx.x;  // 0..32767
  size_t base = (size_t)Ss * Bb * Vv;
  out[base + i] = h_f32[i];
  out[base + Bb * Hh + i] = c_f32[i];
}

// ---------------- host ----------------

extern "C" void kernel_launch(void* const* d_in, const int* in_sizes, int n_in,
                              void* d_out, int out_size, void* d_ws, size_t ws_size,
                              hipStream_t stream) {
  const int* word = (const int*)d_in[0];
  const int* seq = (const int*)d_in[1];
  const float* emb = (const float*)d_in[2];
  const float* Wl = (const float*)d_in[3];
  const float* bl = (const float*)d_in[4];
  const float* Wih = (const float*)d_in[5];
  const float* Whh = (const float*)d_in[6];
  const float* bih = (const float*)d_in[7];
  const float* bhh = (const float*)d_in[8];
  const float* Wz = (const float*)d_in[9];
  const float* bz = (const float*)d_in[10];
  const float* Wr = (const float*)d_in[11];
  const float* br = (const float*)d_in[12];
  const float* Wh = (const float*)d_in[13];
  const float* bh = (const float*)d_in[14];
  const float* Wo = (const float*)d_in[15];
  const float* bo = (const float*)d_in[16];
  float* out = (float*)d_out;

  char* p = (char*)d_ws;
  auto alloc = [&](size_t bytes) -> char* {
    char* q = p;
    p += (bytes + 255) & ~(size_t)255;
    return q;
  };
  float* we_f32 = (float*)alloc(Bb * Ee * 4);
  bf16* hp_h = (bf16*)alloc(Bb * Hh * 2);
  bf16* hp_l = (bf16*)alloc(Bb * Hh * 2);
  float* hl_f32 = (float*)alloc(Bb * Hh * 4);
  float* c_f32 = (float*)alloc(Bb * Hh * 4);
  float* z_f32 = (float*)alloc(Bb * Hh * 4);
  float* h_f32 = (float*)alloc(Bb * Hh * 4);
  bf16* x2h = (bf16*)alloc(Bb * KC * 2);
  bf16* x2l = (bf16*)alloc(Bb * KC * 2);
  bf16* x3h = (bf16*)alloc(Bb * KC * 2);
  bf16* x3l = (bf16*)alloc(Bb * KC * 2);
  bf16* se_h = (bf16*)alloc((size_t)Ss * Bb * Ee * 2);
  bf16* se_l = (bf16*)alloc((size_t)Ss * Bb * Ee * 2);
  bf16* hs_b = (bf16*)alloc((size_t)Ss * Bb * Hh * 2);
  bf16* Wg_h = (bf16*)alloc((size_t)4 * Hh * KC * 2);
  bf16* Wg_l = (bf16*)alloc((size_t)4 * Hh * KC * 2);
  bf16* Wzr_h = (bf16*)alloc((size_t)KC * KC * 2);
  bf16* Wzr_l = (bf16*)alloc((size_t)KC * KC * 2);
  bf16* Wh_h = (bf16*)alloc((size_t)Hh * KC * 2);
  bf16* Wh_l = (bf16*)alloc((size_t)Hh * KC * 2);

  dim3 blk(256);
  k_conv_cat_cols<<<dim3(6, 4096), blk, 0, stream>>>(Wih, Whh, Wg_h, Wg_l);
  k_conv_cat_rows<<<dim3(6, 1536), blk, 0, stream>>>(Wz, Wr, Wzr_h, Wzr_l);
  k_conv_plain<<<dim3(6, 1024), blk, 0, stream>>>(Wh, Wh_h, Wh_l);
  k_gather_we<<<dim3(2, 32), blk, 0, stream>>>(word, emb, we_f32, x2h, x2l);
  k_gather_se<<<dim3(2, Ss * Bb), blk, 0, stream>>>(seq, emb, se_h, se_l);
  k_init_h0<<<8192, blk, 0, stream>>>(we_f32, Wl, bl, c_f32, hp_h, hp_l);

  for (int t = 0; t < Ss; ++t) {
    k_step_gates<<<64, blk, 0, stream>>>(se_h, se_l, t, hp_h, hp_l, Wg_h, Wg_l, bih, bhh,
                                         c_f32, hl_f32, x2h, x2l, x3h, x3l);
    k_step_zr<<<24, blk, 0, stream>>>(x2h, x2l, Wzr_h, Wzr_l, bz, br, we_f32, z_f32, x3h, x3l);
    k_step_hh<<<16, blk, 0, stream>>>(x3h, x3l, Wh_h, Wh_l, bh, hl_f32, z_f32, h_f32, hp_h,
                                      hp_l, hs_b, t);
  }

  k_gemm_out<<<2048, blk, 0, stream>>>(hs_b, Wo, bo, out);
  k_copy_hc<<<128, blk, 0, stream>>>(h_f32, c_f32, out);
}